// Round 1
// baseline (124.881 us; speedup 1.0000x reference)
//
#include <hip/hip_runtime.h>

#define BLK 256
#define ANCH 256
#define MAXM 64  // M=32 in this problem; LDS sized with slack

__global__ __launch_bounds__(BLK) void focal_main(
    const float* __restrict__ cls,
    const float* __restrict__ loc,
    const float* __restrict__ anchors,
    const float* __restrict__ anno,
    int A, int K, int M,
    float* __restrict__ cls_sum, float* __restrict__ loc_sum,
    unsigned int* __restrict__ pos_num)
{
    const int b  = blockIdx.y;
    const int a0 = blockIdx.x * ANCH;
    const int t  = threadIdx.x;
    const int nA = min(ANCH, A - a0);

    __shared__ float s_ann[MAXM * 5];
    __shared__ int   s_status[ANCH];
    __shared__ float s_redc[BLK / 64];
    __shared__ float s_redl[BLK / 64];
    __shared__ unsigned int s_redp[BLK / 64];

    // stage annotations for this image (160 floats)
    for (int i = t; i < M * 5; i += BLK)
        s_ann[i] = anno[(size_t)b * M * 5 + i];
    __syncthreads();

    float loc_part = 0.0f;
    unsigned int pos_part = 0;

    // ---- Phase 1: per-anchor status + loc loss ----
    if (t < nA) {
        const int a = a0 + t;
        const float4 anc = reinterpret_cast<const float4*>(anchors)[a];
        const float ax1 = anc.x, ay1 = anc.y, ax2 = anc.z, ay2 = anc.w;
        const float area_a = (ax2 - ax1) * (ay2 - ay1);

        float best = -1e30f;
        int arg = 0;
        for (int m = 0; m < M; ++m) {
            const float bx1 = s_ann[m * 5 + 0];
            const float by1 = s_ann[m * 5 + 1];
            const float bx2 = s_ann[m * 5 + 2];
            const float by2 = s_ann[m * 5 + 3];
            const float lb  = s_ann[m * 5 + 4];
            float iou;
            if (lb != -1.0f) {
                const float area_b = (bx2 - bx1) * (by2 - by1);
                const float iw = fmaxf(fminf(ax2, bx2) - fmaxf(ax1, bx1), 0.0f);
                const float ih = fmaxf(fminf(ay2, by2) - fmaxf(ay1, by1), 0.0f);
                const float inter = iw * ih;
                const float uni = fmaxf(area_a + area_b - inter, 1e-8f);
                iou = inter / uni;
            } else {
                iou = -1.0f;
            }
            if (iou > best) { best = iou; arg = m; }  // strict > == first-max (jnp argmax)
        }

        const bool pos = best >= 0.5f;
        const bool neg = best < 0.4f;
        s_status[t] = pos ? (int)s_ann[arg * 5 + 4] : (neg ? 254 : 255);

        if (pos) {
            pos_part = 1;
            const float gx1 = s_ann[arg * 5 + 0];
            const float gy1 = s_ann[arg * 5 + 1];
            const float gx2 = s_ann[arg * 5 + 2];
            const float gy2 = s_ann[arg * 5 + 3];
            const float aw = ax2 - ax1, ah = ay2 - ay1;
            const float acx = ax1 + 0.5f * aw, acy = ay1 + 0.5f * ah;
            const float gwr = gx2 - gx1, ghr = gy2 - gy1;
            const float gcx = gx1 + 0.5f * gwr, gcy = gy1 + 0.5f * ghr;
            const float gw = fmaxf(gwr, 1.0f), gh = fmaxf(ghr, 1.0f);
            const float d0 = ((gcx - acx) / aw) / 0.1f;
            const float d1 = ((gcy - acy) / ah) / 0.1f;
            const float d2 = __logf(gw / aw) / 0.2f;
            const float d3 = __logf(gh / ah) / 0.2f;
            const float4 pl = reinterpret_cast<const float4*>(loc)[(size_t)b * A + a];
            const float df[4] = { fabsf(d0 - pl.x), fabsf(d1 - pl.y),
                                  fabsf(d2 - pl.z), fabsf(d3 - pl.w) };
#pragma unroll
            for (int i = 0; i < 4; ++i) {
                const float d = df[i];
                loc_part += (d <= (1.0f / 9.0f)) ? (0.5f * 9.0f) * d * d
                                                 : d - (0.5f / 9.0f);
            }
        }
    } else if (t < ANCH) {
        s_status[t] = 255;  // out-of-range anchors contribute nothing
    }
    __syncthreads();

    // ---- Phase 2: stream classification slab, coalesced float4 ----
    const int KQ = K >> 2;                       // float4s per anchor (K % 4 == 0)
    const float4* cls4 =
        reinterpret_cast<const float4*>(cls + ((size_t)b * A + a0) * K);
    const int total = nA * KQ;
    float cls_part = 0.0f;

    for (int idx = t; idx < total; idx += BLK) {
        const float4 v = cls4[idx];
        const int al = idx / KQ;
        const int st = s_status[al];
        if (st == 255) continue;                 // ignore anchor
        const float pv[4] = { v.x, v.y, v.z, v.w };
        if (st == 254) {                         // negative anchor: all classes bg
#pragma unroll
            for (int i = 0; i < 4; ++i) {
                const float p = fminf(fmaxf(pv[i], 0.0001f), 1.0f - 0.0001f);
                cls_part += 0.75f * p * p * (-__logf(1.0f - p));
            }
        } else {                                 // positive anchor, label = st
            const int c0 = (idx - al * KQ) * 4;
#pragma unroll
            for (int i = 0; i < 4; ++i) {
                const float p = fminf(fmaxf(pv[i], 0.0001f), 1.0f - 0.0001f);
                if (c0 + i == st) {
                    const float q = 1.0f - p;
                    cls_part += 0.25f * q * q * (-__logf(p));
                } else {
                    cls_part += 0.75f * p * p * (-__logf(1.0f - p));
                }
            }
        }
    }

    // ---- reduce within block, one atomic per image per block ----
#pragma unroll
    for (int off = 32; off > 0; off >>= 1) {
        cls_part += __shfl_down(cls_part, off);
        loc_part += __shfl_down(loc_part, off);
        pos_part += __shfl_down(pos_part, off);
    }
    const int wid = t >> 6;
    if ((t & 63) == 0) {
        s_redc[wid] = cls_part;
        s_redl[wid] = loc_part;
        s_redp[wid] = pos_part;
    }
    __syncthreads();
    if (t == 0) {
        float c = 0.0f, l = 0.0f;
        unsigned int pc = 0;
#pragma unroll
        for (int w = 0; w < BLK / 64; ++w) { c += s_redc[w]; l += s_redl[w]; pc += s_redp[w]; }
        atomicAdd(&cls_sum[b], c);
        atomicAdd(&loc_sum[b], l);
        atomicAdd(&pos_num[b], pc);
    }
}

__global__ void focal_final(const float* __restrict__ anno, int B, int M,
                            const float* __restrict__ cls_sum,
                            const float* __restrict__ loc_sum,
                            const unsigned int* __restrict__ pos_num,
                            float* __restrict__ out)
{
    __shared__ float s_c[64], s_l[64];
    const int t = threadIdx.x;
    float c = 0.0f, l = 0.0f;
    if (t < B) {
        int nv = 0;
        for (int m = 0; m < M; ++m)
            nv += (anno[(size_t)t * M * 5 + m * 5 + 4] != -1.0f) ? 1 : 0;
        const unsigned int pn = pos_num[t];
        const float pnf = (float)pn;
        c = cls_sum[t] / fmaxf(pnf, 1.0f);
        l = (pn > 0) ? loc_sum[t] / fmaxf(pnf * 4.0f, 1.0f) : 0.0f;
        if (nv == 0) { c = 0.0f; l = 0.0f; }
    }
    s_c[t] = c; s_l[t] = l;
    __syncthreads();
    if (t == 0) {
        float cs = 0.0f, ls = 0.0f;
        for (int i = 0; i < B; ++i) { cs += s_c[i]; ls += s_l[i]; }
        out[0] = cs / (float)B;
        out[1] = ls / (float)B;
    }
}

extern "C" void kernel_launch(void* const* d_in, const int* in_sizes, int n_in,
                              void* d_out, int out_size, void* d_ws, size_t ws_size,
                              hipStream_t stream) {
    const float* cls     = (const float*)d_in[0];
    const float* loc     = (const float*)d_in[1];
    const float* anchors = (const float*)d_in[2];
    const float* anno    = (const float*)d_in[3];

    const int A  = in_sizes[2] / 4;
    const long long BA = (long long)in_sizes[1] / 4;   // B*A
    const int B  = (int)(BA / A);
    const int K  = (int)((long long)in_sizes[0] / BA);
    const int M  = in_sizes[3] / (B * 5);

    float* cls_sum = (float*)d_ws;
    float* loc_sum = cls_sum + B;
    unsigned int* pos_num = (unsigned int*)(loc_sum + B);
    hipMemsetAsync(d_ws, 0, (size_t)B * 3 * sizeof(float), stream);

    dim3 grid((A + ANCH - 1) / ANCH, B);
    focal_main<<<grid, BLK, 0, stream>>>(cls, loc, anchors, anno, A, K, M,
                                         cls_sum, loc_sum, pos_num);
    focal_final<<<1, 64, 0, stream>>>(anno, B, M, cls_sum, loc_sum, pos_num,
                                      (float*)d_out);
}

// Round 2
// 116.139 us; speedup vs baseline: 1.0753x; 1.0753x over previous
//
#include <hip/hip_runtime.h>

#define BLK 256
#define ANCH 256
#define MAXM 64  // M=32 in this problem; LDS sized with slack

// Branch-free focal contribution of one float4 (4 consecutive classes c0..c0+3)
// st: 0..K-1 = positive anchor's label, 254 = negative, 255 = ignore.
// Note: st==254 never equals a class index, so negatives fall out naturally.
__device__ __forceinline__ float eval4(const float4 v, const int st, const int c0) {
    constexpr float LN2 = 0.6931471805599453f;
    const float pv[4] = { v.x, v.y, v.z, v.w };
    float acc = 0.0f;
#pragma unroll
    for (int i = 0; i < 4; ++i) {
        const float p  = fminf(fmaxf(pv[i], 0.0001f), 1.0f - 0.0001f);
        const bool  y  = (c0 + i == st);
        const float pt = y ? p : 1.0f - p;
        const float a  = y ? 0.25f * LN2 : 0.75f * LN2;   // ln2 folded into alpha
        const float q  = 1.0f - pt;
        acc = fmaf(a * q * q, -__log2f(pt), acc);         // -ln(pt)*alpha*q^2
    }
    return (st == 255) ? 0.0f : acc;
}

template <int KQ_C>
__global__ __launch_bounds__(BLK) void focal_main(
    const float* __restrict__ cls,
    const float* __restrict__ loc,
    const float* __restrict__ anchors,
    const float* __restrict__ anno,
    int A, int kq_dyn, int M,
    float* __restrict__ cls_sum, float* __restrict__ loc_sum,
    unsigned int* __restrict__ pos_num)
{
    const int KQ = KQ_C ? KQ_C : kq_dyn;   // compile-time when specialized
    const int b  = blockIdx.y;
    const int a0 = blockIdx.x * ANCH;
    const int t  = threadIdx.x;
    const int nA = min(ANCH, A - a0);

    __shared__ float s_ann[MAXM * 5];
    __shared__ int   s_status[ANCH];
    __shared__ float s_redc[BLK / 64];
    __shared__ float s_redl[BLK / 64];
    __shared__ unsigned int s_redp[BLK / 64];

    for (int i = t; i < M * 5; i += BLK)
        s_ann[i] = anno[(size_t)b * M * 5 + i];
    __syncthreads();

    float loc_part = 0.0f;
    unsigned int pos_part = 0;

    // ---- Phase 1: per-anchor status + loc loss (1/20 of the work) ----
    if (t < nA) {
        const int a = a0 + t;
        const float4 anc = reinterpret_cast<const float4*>(anchors)[a];
        const float ax1 = anc.x, ay1 = anc.y, ax2 = anc.z, ay2 = anc.w;
        const float area_a = (ax2 - ax1) * (ay2 - ay1);

        float best = -1e30f;
        int arg = 0;
        for (int m = 0; m < M; ++m) {
            const float bx1 = s_ann[m * 5 + 0];
            const float by1 = s_ann[m * 5 + 1];
            const float bx2 = s_ann[m * 5 + 2];
            const float by2 = s_ann[m * 5 + 3];
            const float lb  = s_ann[m * 5 + 4];
            float iou;
            if (lb != -1.0f) {
                const float area_b = (bx2 - bx1) * (by2 - by1);
                const float iw = fmaxf(fminf(ax2, bx2) - fmaxf(ax1, bx1), 0.0f);
                const float ih = fmaxf(fminf(ay2, by2) - fmaxf(ay1, by1), 0.0f);
                const float inter = iw * ih;
                const float uni = fmaxf(area_a + area_b - inter, 1e-8f);
                iou = inter / uni;
            } else {
                iou = -1.0f;
            }
            if (iou > best) { best = iou; arg = m; }  // strict > == first-max (jnp argmax)
        }

        const bool pos = best >= 0.5f;
        const bool neg = best < 0.4f;
        s_status[t] = pos ? (int)s_ann[arg * 5 + 4] : (neg ? 254 : 255);

        if (pos) {
            pos_part = 1;
            const float gx1 = s_ann[arg * 5 + 0];
            const float gy1 = s_ann[arg * 5 + 1];
            const float gx2 = s_ann[arg * 5 + 2];
            const float gy2 = s_ann[arg * 5 + 3];
            const float aw = ax2 - ax1, ah = ay2 - ay1;
            const float acx = ax1 + 0.5f * aw, acy = ay1 + 0.5f * ah;
            const float gwr = gx2 - gx1, ghr = gy2 - gy1;
            const float gcx = gx1 + 0.5f * gwr, gcy = gy1 + 0.5f * ghr;
            const float gw = fmaxf(gwr, 1.0f), gh = fmaxf(ghr, 1.0f);
            const float d0 = ((gcx - acx) / aw) / 0.1f;
            const float d1 = ((gcy - acy) / ah) / 0.1f;
            const float d2 = __logf(gw / aw) / 0.2f;
            const float d3 = __logf(gh / ah) / 0.2f;
            const float4 pl = reinterpret_cast<const float4*>(loc)[(size_t)b * A + a];
            const float df[4] = { fabsf(d0 - pl.x), fabsf(d1 - pl.y),
                                  fabsf(d2 - pl.z), fabsf(d3 - pl.w) };
#pragma unroll
            for (int i = 0; i < 4; ++i) {
                const float d = df[i];
                loc_part += (d <= (1.0f / 9.0f)) ? (0.5f * 9.0f) * d * d
                                                 : d - (0.5f / 9.0f);
            }
        }
    } else if (t < ANCH) {
        s_status[t] = 255;
    }
    __syncthreads();

    // ---- Phase 2: stream classification slab, unrolled x5, batched loads ----
    const float4* __restrict__ cls4 =
        reinterpret_cast<const float4*>(cls + ((size_t)b * A + a0) * (KQ * 4));
    const int total = nA * KQ;
    float cls_part = 0.0f;

    constexpr int UN = 5;
    int idx = t;
    for (; idx + (UN - 1) * BLK < total; idx += UN * BLK) {
        float4 v[UN];
#pragma unroll
        for (int u = 0; u < UN; ++u)
            v[u] = cls4[idx + u * BLK];          // 5 independent loads in flight
#pragma unroll
        for (int u = 0; u < UN; ++u) {
            const int id = idx + u * BLK;
            const int al = id / KQ;              // constant divisor -> magic mul
            const int c0 = (id - al * KQ) * 4;
            cls_part += eval4(v[u], s_status[al], c0);
        }
    }
    for (; idx < total; idx += BLK) {            // tail (last partial block only)
        const int al = idx / KQ;
        const int c0 = (idx - al * KQ) * 4;
        cls_part += eval4(cls4[idx], s_status[al], c0);
    }

    // ---- reduce within block, one atomic per image per block ----
#pragma unroll
    for (int off = 32; off > 0; off >>= 1) {
        cls_part += __shfl_down(cls_part, off);
        loc_part += __shfl_down(loc_part, off);
        pos_part += __shfl_down(pos_part, off);
    }
    const int wid = t >> 6;
    if ((t & 63) == 0) {
        s_redc[wid] = cls_part;
        s_redl[wid] = loc_part;
        s_redp[wid] = pos_part;
    }
    __syncthreads();
    if (t == 0) {
        float c = 0.0f, l = 0.0f;
        unsigned int pc = 0;
#pragma unroll
        for (int w = 0; w < BLK / 64; ++w) { c += s_redc[w]; l += s_redl[w]; pc += s_redp[w]; }
        atomicAdd(&cls_sum[b], c);
        atomicAdd(&loc_sum[b], l);
        atomicAdd(&pos_num[b], pc);
    }
}

__global__ void focal_final(const float* __restrict__ anno, int B, int M,
                            const float* __restrict__ cls_sum,
                            const float* __restrict__ loc_sum,
                            const unsigned int* __restrict__ pos_num,
                            float* __restrict__ out)
{
    __shared__ float s_c[64], s_l[64];
    const int t = threadIdx.x;
    float c = 0.0f, l = 0.0f;
    if (t < B) {
        int nv = 0;
        for (int m = 0; m < M; ++m)
            nv += (anno[(size_t)t * M * 5 + m * 5 + 4] != -1.0f) ? 1 : 0;
        const unsigned int pn = pos_num[t];
        const float pnf = (float)pn;
        c = cls_sum[t] / fmaxf(pnf, 1.0f);
        l = (pn > 0) ? loc_sum[t] / fmaxf(pnf * 4.0f, 1.0f) : 0.0f;
        if (nv == 0) { c = 0.0f; l = 0.0f; }
    }
    s_c[t] = c; s_l[t] = l;
    __syncthreads();
    if (t == 0) {
        float cs = 0.0f, ls = 0.0f;
        for (int i = 0; i < B; ++i) { cs += s_c[i]; ls += s_l[i]; }
        out[0] = cs / (float)B;
        out[1] = ls / (float)B;
    }
}

extern "C" void kernel_launch(void* const* d_in, const int* in_sizes, int n_in,
                              void* d_out, int out_size, void* d_ws, size_t ws_size,
                              hipStream_t stream) {
    const float* cls     = (const float*)d_in[0];
    const float* loc     = (const float*)d_in[1];
    const float* anchors = (const float*)d_in[2];
    const float* anno    = (const float*)d_in[3];

    const int A  = in_sizes[2] / 4;
    const long long BA = (long long)in_sizes[1] / 4;   // B*A
    const int B  = (int)(BA / A);
    const int K  = (int)((long long)in_sizes[0] / BA);
    const int M  = in_sizes[3] / (B * 5);
    const int KQ = K >> 2;

    float* cls_sum = (float*)d_ws;
    float* loc_sum = cls_sum + B;
    unsigned int* pos_num = (unsigned int*)(loc_sum + B);
    hipMemsetAsync(d_ws, 0, (size_t)B * 3 * sizeof(float), stream);

    dim3 grid((A + ANCH - 1) / ANCH, B);
    if (KQ == 20) {
        focal_main<20><<<grid, BLK, 0, stream>>>(cls, loc, anchors, anno, A, KQ, M,
                                                 cls_sum, loc_sum, pos_num);
    } else {
        focal_main<0><<<grid, BLK, 0, stream>>>(cls, loc, anchors, anno, A, KQ, M,
                                                cls_sum, loc_sum, pos_num);
    }
    focal_final<<<1, 64, 0, stream>>>(anno, B, M, cls_sum, loc_sum, pos_num,
                                      (float*)d_out);
}

// Round 3
// 112.797 us; speedup vs baseline: 1.1071x; 1.0296x over previous
//
#include <hip/hip_runtime.h>

#define BLK 256
#define ANCH 256
#define MAXM 64  // M=32 here; slack

constexpr float LN2 = 0.6931471805599453f;

// Background focal partial for one float4:  sum_i p_i^2 * log2(1 - p_i)   (<= 0)
__device__ __forceinline__ float bg4(const float4 v) {
    const float pv[4] = { v.x, v.y, v.z, v.w };
    float acc = 0.0f;
#pragma unroll
    for (int i = 0; i < 4; ++i) {
        const float p = fminf(fmaxf(pv[i], 0.0001f), 1.0f - 0.0001f);
        acc = fmaf(p * p, __log2f(1.0f - p), acc);
    }
    return acc;
}

// One quad (4 consecutive classes c0..c0+3) of one anchor with status st.
// st: 0..K-1 = positive label, 254 = negative, 255 = ignore.
__device__ __forceinline__ void quad(const float4 v, const int st, const int c0,
                                     float& cls_part) {
    const float s = bg4(v);
    cls_part = fmaf(s, (st == 255) ? 0.0f : -0.75f * LN2, cls_part);
    const unsigned d = (unsigned)(st - c0);
    if (d < 4u) {                       // rare: this quad holds the positive class
        float p = v.x;
        p = (d == 1) ? v.y : p;
        p = (d == 2) ? v.z : p;
        p = (d == 3) ? v.w : p;
        p = fminf(fmaxf(p, 0.0001f), 1.0f - 0.0001f);
        const float bg = p * p * __log2f(1.0f - p);
        const float q  = 1.0f - p;
        const float fg = q * q * __log2f(p);
        cls_part += -LN2 * (0.25f * fg - 0.75f * bg);   // add fg-term, remove bg-term
    }
}

template <int KQ_C>
__global__ __launch_bounds__(BLK) void focal_main(
    const float* __restrict__ cls,
    const float* __restrict__ loc,
    const float* __restrict__ anchors,
    const float* __restrict__ anno,
    int A, int kq_dyn, int M,
    float* __restrict__ cls_sum, float* __restrict__ loc_sum,
    unsigned int* __restrict__ pos_num)
{
    const int KQ = KQ_C ? KQ_C : kq_dyn;
    const int b  = blockIdx.y;
    const int a0 = blockIdx.x * ANCH;
    const int t  = threadIdx.x;
    const int nA = min(ANCH, A - a0);

    __shared__ float4 s_box[MAXM];
    __shared__ float  s_lab[MAXM];
    __shared__ int    s_status[ANCH];
    __shared__ float  s_redc[BLK / 64];
    __shared__ float  s_redl[BLK / 64];
    __shared__ unsigned int s_redp[BLK / 64];

    const float4* __restrict__ cls4 =
        reinterpret_cast<const float4*>(cls) + ((size_t)b * A + a0) * KQ;
    const bool full = (KQ_C == 20) && (nA == ANCH);

#define LOADB(R, BK)                                                        \
    do {                                                                    \
        _Pragma("unroll") for (int u_ = 0; u_ < 4; ++u_)                    \
            R[u_] = cls4[t + ((BK) * 4 + u_) * BLK];                        \
    } while (0)

#define EVALB(R, BK)                                                        \
    do {                                                                    \
        _Pragma("unroll") for (int u_ = 0; u_ < 4; ++u_) {                  \
            const int idx_ = t + ((BK) * 4 + u_) * BLK;                     \
            const int al_  = idx_ / 20;                                     \
            const int c0_  = (idx_ - al_ * 20) * 4;                         \
            quad(R[u_], s_status[al_], c0_, cls_part);                      \
        }                                                                   \
    } while (0)

    float4 va[4], vb[4];
    if (full) LOADB(va, 0);           // batch 0 in flight across phase 1

    // stage annotations as SoA (boxes float4-aligned + labels)
    if (t < M) {
        const float* ap = anno + ((size_t)b * M + t) * 5;
        s_box[t] = make_float4(ap[0], ap[1], ap[2], ap[3]);
        s_lab[t] = ap[4];
    }
    __syncthreads();

    float loc_part = 0.0f;
    unsigned int pos_part = 0;

    // ---- Phase 1: per-anchor status + loc loss ----
    if (t < nA) {
        const int a = a0 + t;
        const float4 anc = reinterpret_cast<const float4*>(anchors)[a];
        const float ax1 = anc.x, ay1 = anc.y, ax2 = anc.z, ay2 = anc.w;
        const float area_a = (ax2 - ax1) * (ay2 - ay1);

        float best = -1e30f;
        int arg = 0;
        for (int m = 0; m < M; ++m) {
            const float4 bb = s_box[m];          // ds_read_b128, wave-uniform
            const float lb  = s_lab[m];
            float iou;
            if (lb != -1.0f) {
                const float area_b = (bb.z - bb.x) * (bb.w - bb.y);
                const float iw = fmaxf(fminf(ax2, bb.z) - fmaxf(ax1, bb.x), 0.0f);
                const float ih = fmaxf(fminf(ay2, bb.w) - fmaxf(ay1, bb.y), 0.0f);
                const float inter = iw * ih;
                const float uni = fmaxf(area_a + area_b - inter, 1e-8f);
                iou = inter / uni;
            } else {
                iou = -1.0f;
            }
            if (iou > best) { best = iou; arg = m; }  // strict > == jnp first-max
        }

        const bool pos = best >= 0.5f;
        const bool neg = best < 0.4f;
        s_status[t] = pos ? (int)s_lab[arg] : (neg ? 254 : 255);

        if (pos) {
            pos_part = 1;
            const float4 g = s_box[arg];
            const float aw = ax2 - ax1, ah = ay2 - ay1;
            const float acx = ax1 + 0.5f * aw, acy = ay1 + 0.5f * ah;
            const float gwr = g.z - g.x, ghr = g.w - g.y;
            const float gcx = g.x + 0.5f * gwr, gcy = g.y + 0.5f * ghr;
            const float gw = fmaxf(gwr, 1.0f), gh = fmaxf(ghr, 1.0f);
            const float d0 = ((gcx - acx) / aw) / 0.1f;
            const float d1 = ((gcy - acy) / ah) / 0.1f;
            const float d2 = __logf(gw / aw) / 0.2f;
            const float d3 = __logf(gh / ah) / 0.2f;
            const float4 pl = reinterpret_cast<const float4*>(loc)[(size_t)b * A + a];
            const float df[4] = { fabsf(d0 - pl.x), fabsf(d1 - pl.y),
                                  fabsf(d2 - pl.z), fabsf(d3 - pl.w) };
#pragma unroll
            for (int i = 0; i < 4; ++i) {
                const float d = df[i];
                loc_part += (d <= (1.0f / 9.0f)) ? (0.5f * 9.0f) * d * d
                                                 : d - (0.5f / 9.0f);
            }
        }
    } else if (t < ANCH) {
        s_status[t] = 255;
    }
    __syncthreads();

    // ---- Phase 2: stream cls slab; ping-pong pipeline, 8 loads in flight ----
    float cls_part = 0.0f;
    if (full) {
        LOADB(vb, 1);
        EVALB(va, 0); LOADB(va, 2);
        EVALB(vb, 1); LOADB(vb, 3);
        EVALB(va, 2); LOADB(va, 4);
        EVALB(vb, 3);
        EVALB(va, 4);
    } else {
        const int total = nA * KQ;
        for (int idx = t; idx < total; idx += BLK) {
            const float4 v = cls4[idx];
            const int al = idx / KQ;
            const int c0 = (idx - al * KQ) * 4;
            quad(v, s_status[al], c0, cls_part);
        }
    }

    // ---- reduce within block, one atomic per image per block ----
#pragma unroll
    for (int off = 32; off > 0; off >>= 1) {
        cls_part += __shfl_down(cls_part, off);
        loc_part += __shfl_down(loc_part, off);
        pos_part += __shfl_down(pos_part, off);
    }
    const int wid = t >> 6;
    if ((t & 63) == 0) {
        s_redc[wid] = cls_part;
        s_redl[wid] = loc_part;
        s_redp[wid] = pos_part;
    }
    __syncthreads();
    if (t == 0) {
        float c = 0.0f, l = 0.0f;
        unsigned int pc = 0;
#pragma unroll
        for (int w = 0; w < BLK / 64; ++w) { c += s_redc[w]; l += s_redl[w]; pc += s_redp[w]; }
        atomicAdd(&cls_sum[b], c);
        atomicAdd(&loc_sum[b], l);
        atomicAdd(&pos_num[b], pc);
    }
#undef LOADB
#undef EVALB
}

__global__ void focal_final(const float* __restrict__ anno, int B, int M,
                            const float* __restrict__ cls_sum,
                            const float* __restrict__ loc_sum,
                            const unsigned int* __restrict__ pos_num,
                            float* __restrict__ out)
{
    __shared__ float s_c[64], s_l[64];
    const int t = threadIdx.x;
    float c = 0.0f, l = 0.0f;
    if (t < B) {
        int nv = 0;
        for (int m = 0; m < M; ++m)
            nv += (anno[(size_t)t * M * 5 + m * 5 + 4] != -1.0f) ? 1 : 0;
        const unsigned int pn = pos_num[t];
        const float pnf = (float)pn;
        c = cls_sum[t] / fmaxf(pnf, 1.0f);
        l = (pn > 0) ? loc_sum[t] / fmaxf(pnf * 4.0f, 1.0f) : 0.0f;
        if (nv == 0) { c = 0.0f; l = 0.0f; }
    }
    s_c[t] = c; s_l[t] = l;
    __syncthreads();
    if (t == 0) {
        float cs = 0.0f, ls = 0.0f;
        for (int i = 0; i < B; ++i) { cs += s_c[i]; ls += s_l[i]; }
        out[0] = cs / (float)B;
        out[1] = ls / (float)B;
    }
}

extern "C" void kernel_launch(void* const* d_in, const int* in_sizes, int n_in,
                              void* d_out, int out_size, void* d_ws, size_t ws_size,
                              hipStream_t stream) {
    const float* cls     = (const float*)d_in[0];
    const float* loc     = (const float*)d_in[1];
    const float* anchors = (const float*)d_in[2];
    const float* anno    = (const float*)d_in[3];

    const int A  = in_sizes[2] / 4;
    const long long BA = (long long)in_sizes[1] / 4;   // B*A
    const int B  = (int)(BA / A);
    const int K  = (int)((long long)in_sizes[0] / BA);
    const int M  = in_sizes[3] / (B * 5);
    const int KQ = K >> 2;

    float* cls_sum = (float*)d_ws;
    float* loc_sum = cls_sum + B;
    unsigned int* pos_num = (unsigned int*)(loc_sum + B);
    hipMemsetAsync(d_ws, 0, (size_t)B * 3 * sizeof(float), stream);

    dim3 grid((A + ANCH - 1) / ANCH, B);
    if (KQ == 20) {
        focal_main<20><<<grid, BLK, 0, stream>>>(cls, loc, anchors, anno, A, KQ, M,
                                                 cls_sum, loc_sum, pos_num);
    } else {
        focal_main<0><<<grid, BLK, 0, stream>>>(cls, loc, anchors, anno, A, KQ, M,
                                                cls_sum, loc_sum, pos_num);
    }
    focal_final<<<1, 64, 0, stream>>>(anno, B, M, cls_sum, loc_sum, pos_num,
                                      (float*)d_out);
}

// Round 4
// 58.677 us; speedup vs baseline: 2.1283x; 1.9223x over previous
//
#include <hip/hip_runtime.h>

#define BLK 256
#define ANCH 256

constexpr float LN2 = 0.6931471805599453f;

// Background focal partial for one float4:  sum_i p_i^2 * log2(1 - p_i)   (<= 0)
__device__ __forceinline__ float bg4(const float4 v) {
    const float pv[4] = { v.x, v.y, v.z, v.w };
    float acc = 0.0f;
#pragma unroll
    for (int i = 0; i < 4; ++i) {
        const float p = fminf(fmaxf(pv[i], 0.0001f), 1.0f - 0.0001f);
        acc = fmaf(p * p, __log2f(1.0f - p), acc);
    }
    return acc;
}

// One quad (4 consecutive classes c0..c0+3) of one anchor with status st.
// st: 0..K-1 = positive label, 254 = negative, 255 = ignore.
__device__ __forceinline__ void quad(const float4 v, const int st, const int c0,
                                     float& cls_part) {
    const float s = bg4(v);
    cls_part = fmaf(s, (st == 255) ? 0.0f : -0.75f * LN2, cls_part);
    const unsigned d = (unsigned)(st - c0);
    if (d < 4u) {                       // rare: this quad holds the positive class
        float p = v.x;
        p = (d == 1) ? v.y : p;
        p = (d == 2) ? v.z : p;
        p = (d == 3) ? v.w : p;
        p = fminf(fmaxf(p, 0.0001f), 1.0f - 0.0001f);
        const float bg = p * p * __log2f(1.0f - p);
        const float q  = 1.0f - p;
        const float fg = q * q * __log2f(p);
        cls_part += -LN2 * (0.25f * fg - 0.75f * bg);   // add fg-term, remove bg-term
    }
}

template <int KQ_C, int M_C>
__global__ __launch_bounds__(BLK) void focal_main(
    const float* __restrict__ cls,
    const float* __restrict__ loc,
    const float* __restrict__ anchors,
    const float* __restrict__ anno,
    int A, int kq_dyn, int m_dyn, int B, int NBX,
    float* __restrict__ part)          // [3][B][NBX] partials, no atomics
{
    const int KQ = KQ_C ? KQ_C : kq_dyn;
    const int M  = M_C  ? M_C  : m_dyn;
    const int b  = blockIdx.y;
    const int bx = blockIdx.x;
    const int a0 = bx * ANCH;
    const int t  = threadIdx.x;
    const int nA = min(ANCH, A - a0);

    __shared__ float4 s_box[64];
    __shared__ float  s_lab[64];
    __shared__ int    s_status[ANCH];
    __shared__ float  s_redc[BLK / 64];
    __shared__ float  s_redl[BLK / 64];
    __shared__ float  s_redp[BLK / 64];

    const float4* __restrict__ cls4 =
        reinterpret_cast<const float4*>(cls) + ((size_t)b * A + a0) * KQ;
    const bool full = (KQ_C == 20) && (nA == ANCH);

#define LOADB(R, BK)                                                        \
    do {                                                                    \
        _Pragma("unroll") for (int u_ = 0; u_ < 4; ++u_)                    \
            R[u_] = cls4[t + ((BK) * 4 + u_) * BLK];                        \
    } while (0)

#define EVALB(R, BK)                                                        \
    do {                                                                    \
        _Pragma("unroll") for (int u_ = 0; u_ < 4; ++u_) {                  \
            const int idx_ = t + ((BK) * 4 + u_) * BLK;                     \
            const int al_  = idx_ / 20;                                     \
            const int c0_  = (idx_ - al_ * 20) * 4;                         \
            quad(R[u_], s_status[al_], c0_, cls_part);                      \
        }                                                                   \
    } while (0)

    float4 va[4], vb[4];
    if (full) { LOADB(va, 0); LOADB(vb, 1); }   // 8 loads hidden under phase 1

    // stage annotations as SoA (boxes float4-aligned + labels)
    if (t < M) {
        const float* ap = anno + ((size_t)b * M + t) * 5;
        s_box[t] = make_float4(ap[0], ap[1], ap[2], ap[3]);
        s_lab[t] = ap[4];
    }
    __syncthreads();

    float loc_part = 0.0f;
    float pos_part = 0.0f;

    // ---- Phase 1: per-anchor status + loc loss (M unrolled when M_C) ----
    if (t < nA) {
        const int a = a0 + t;
        const float4 anc = reinterpret_cast<const float4*>(anchors)[a];
        const float ax1 = anc.x, ay1 = anc.y, ax2 = anc.z, ay2 = anc.w;
        const float area_a = (ax2 - ax1) * (ay2 - ay1);

        float best = -1e30f;
        int arg = 0;
#pragma unroll
        for (int m = 0; m < M; ++m) {
            const float4 bb = s_box[m];
            const float lb  = s_lab[m];
            float iou;
            if (lb != -1.0f) {
                const float area_b = (bb.z - bb.x) * (bb.w - bb.y);
                const float iw = fmaxf(fminf(ax2, bb.z) - fmaxf(ax1, bb.x), 0.0f);
                const float ih = fmaxf(fminf(ay2, bb.w) - fmaxf(ay1, bb.y), 0.0f);
                const float inter = iw * ih;
                const float uni = fmaxf(area_a + area_b - inter, 1e-8f);
                iou = inter / uni;
            } else {
                iou = -1.0f;
            }
            if (iou > best) { best = iou; arg = m; }  // strict > == jnp first-max
        }

        const bool pos = best >= 0.5f;
        const bool neg = best < 0.4f;
        s_status[t] = pos ? (int)s_lab[arg] : (neg ? 254 : 255);

        if (pos) {
            pos_part = 1.0f;
            const float4 g = s_box[arg];
            const float aw = ax2 - ax1, ah = ay2 - ay1;
            const float acx = ax1 + 0.5f * aw, acy = ay1 + 0.5f * ah;
            const float gwr = g.z - g.x, ghr = g.w - g.y;
            const float gcx = g.x + 0.5f * gwr, gcy = g.y + 0.5f * ghr;
            const float gw = fmaxf(gwr, 1.0f), gh = fmaxf(ghr, 1.0f);
            const float d0 = ((gcx - acx) / aw) / 0.1f;
            const float d1 = ((gcy - acy) / ah) / 0.1f;
            const float d2 = __logf(gw / aw) / 0.2f;
            const float d3 = __logf(gh / ah) / 0.2f;
            const float4 pl = reinterpret_cast<const float4*>(loc)[(size_t)b * A + a];
            const float df[4] = { fabsf(d0 - pl.x), fabsf(d1 - pl.y),
                                  fabsf(d2 - pl.z), fabsf(d3 - pl.w) };
#pragma unroll
            for (int i = 0; i < 4; ++i) {
                const float d = df[i];
                loc_part += (d <= (1.0f / 9.0f)) ? (0.5f * 9.0f) * d * d
                                                 : d - (0.5f / 9.0f);
            }
        }
    } else if (t < ANCH) {
        s_status[t] = 255;
    }
    __syncthreads();

    // ---- Phase 2: stream cls slab; ping-pong pipeline, 8 loads in flight ----
    float cls_part = 0.0f;
    if (full) {
        EVALB(va, 0); LOADB(va, 2);
        EVALB(vb, 1); LOADB(vb, 3);
        EVALB(va, 2); LOADB(va, 4);
        EVALB(vb, 3);
        EVALB(va, 4);
    } else {
        const int total = nA * KQ;
        for (int idx = t; idx < total; idx += BLK) {
            const float4 v = cls4[idx];
            const int al = idx / KQ;
            const int c0 = (idx - al * KQ) * 4;
            quad(v, s_status[al], c0, cls_part);
        }
    }

    // ---- reduce within block, write per-block partials (NO atomics) ----
#pragma unroll
    for (int off = 32; off > 0; off >>= 1) {
        cls_part += __shfl_down(cls_part, off);
        loc_part += __shfl_down(loc_part, off);
        pos_part += __shfl_down(pos_part, off);
    }
    const int wid = t >> 6;
    if ((t & 63) == 0) {
        s_redc[wid] = cls_part;
        s_redl[wid] = loc_part;
        s_redp[wid] = pos_part;
    }
    __syncthreads();
    if (t == 0) {
        float c = 0.0f, l = 0.0f, p = 0.0f;
#pragma unroll
        for (int w = 0; w < BLK / 64; ++w) { c += s_redc[w]; l += s_redl[w]; p += s_redp[w]; }
        part[(size_t)b * NBX + bx]           = c;
        part[(size_t)(B + b) * NBX + bx]     = l;
        part[(size_t)(2 * B + b) * NBX + bx] = p;
    }
#undef LOADB
#undef EVALB
}

__global__ void focal_final(const float* __restrict__ anno, int B, int M, int NBX,
                            const float* __restrict__ part,
                            float* __restrict__ out)
{
    __shared__ float s_c[32], s_l[32];
    const int t = threadIdx.x;
    const int lane = t & 31;
    const int ngrp = blockDim.x >> 5;
    if (t < 32) { s_c[t] = 0.0f; s_l[t] = 0.0f; }
    __syncthreads();

    for (int img = t >> 5; img < B; img += ngrp) {
        float c = 0.0f, l = 0.0f, p = 0.0f, nv = 0.0f;
        const float* pc = part + (size_t)img * NBX;
        const float* pl = part + (size_t)(B + img) * NBX;
        const float* pp = part + (size_t)(2 * B + img) * NBX;
        for (int e = lane; e < NBX; e += 32) { c += pc[e]; l += pl[e]; p += pp[e]; }
        for (int m = lane; m < M; m += 32)
            nv += (anno[((size_t)img * M + m) * 5 + 4] != -1.0f) ? 1.0f : 0.0f;
#pragma unroll
        for (int off = 16; off > 0; off >>= 1) {
            c  += __shfl_down(c,  off, 32);
            l  += __shfl_down(l,  off, 32);
            p  += __shfl_down(p,  off, 32);
            nv += __shfl_down(nv, off, 32);
        }
        if (lane == 0) {
            float cls_l = c / fmaxf(p, 1.0f);
            float loc_l = (p > 0.0f) ? l / fmaxf(4.0f * p, 1.0f) : 0.0f;
            if (nv == 0.0f) { cls_l = 0.0f; loc_l = 0.0f; }
            s_c[img] = cls_l;
            s_l[img] = loc_l;
        }
    }
    __syncthreads();
    if (t == 0) {
        float cs = 0.0f, ls = 0.0f;
        for (int i = 0; i < B; ++i) { cs += s_c[i]; ls += s_l[i]; }
        out[0] = cs / (float)B;
        out[1] = ls / (float)B;
    }
}

extern "C" void kernel_launch(void* const* d_in, const int* in_sizes, int n_in,
                              void* d_out, int out_size, void* d_ws, size_t ws_size,
                              hipStream_t stream) {
    const float* cls     = (const float*)d_in[0];
    const float* loc     = (const float*)d_in[1];
    const float* anchors = (const float*)d_in[2];
    const float* anno    = (const float*)d_in[3];

    const int A  = in_sizes[2] / 4;
    const long long BA = (long long)in_sizes[1] / 4;   // B*A
    const int B  = (int)(BA / A);
    const int K  = (int)((long long)in_sizes[0] / BA);
    const int M  = in_sizes[3] / (B * 5);
    const int KQ = K >> 2;
    const int NBX = (A + ANCH - 1) / ANCH;

    float* part = (float*)d_ws;  // [3][B][NBX], every slot written each call

    dim3 grid(NBX, B);
    if (KQ == 20 && M == 32) {
        focal_main<20, 32><<<grid, BLK, 0, stream>>>(cls, loc, anchors, anno,
                                                     A, KQ, M, B, NBX, part);
    } else {
        focal_main<0, 0><<<grid, BLK, 0, stream>>>(cls, loc, anchors, anno,
                                                   A, KQ, M, B, NBX, part);
    }
    focal_final<<<1, 256, 0, stream>>>(anno, B, M, NBX, part, (float*)d_out);
}